// Round 2
// baseline (955.681 us; speedup 1.0000x reference)
//
#include <hip/hip_runtime.h>

typedef unsigned short ushortT;
typedef unsigned int uintT;

typedef __bf16 bf16x8 __attribute__((ext_vector_type(8)));
typedef float f32x4 __attribute__((ext_vector_type(4)));

__device__ __forceinline__ ushortT f2bf(float f) {
    union { float f; uintT i; } v; v.f = f;
    uintT r = v.i + 0x7FFFu + ((v.i >> 16) & 1u);   // round-to-nearest-even
    return (ushortT)(r >> 16);
}

__device__ __forceinline__ void gld16(const ushortT* g, ushortT* l) {
    __builtin_amdgcn_global_load_lds(
        (const __attribute__((address_space(1))) void*)g,
        (__attribute__((address_space(3))) void*)l, 16, 0, 0);
}

// ---------------- W0 f32 [1204][256] -> W0T bf16 padded [256][1216] ----------------
__global__ void prep_w(const float* __restrict__ W0, ushortT* __restrict__ W0T) {
    int tid = blockIdx.x * 256 + threadIdx.x;
    if (tid >= 256 * 1216) return;
    int n = tid / 1216, k = tid % 1216;
    ushortT v = 0;
    int kk = -1;
    if (k < 602) kk = k;
    else if (k >= 608 && k < 1210) kk = k - 6;   // second half of concat
    if (kk >= 0) v = f2bf(W0[kk * 256 + n]);
    W0T[n * 1216 + k] = v;
}

// ------- self-features f32 -> bf16 into cat matrix, cols [0,608), pad zero -------
__global__ void copy_pad(const float* __restrict__ src, ushortT* __restrict__ dst, int rows) {
    int tid = blockIdx.x * 256 + threadIdx.x;       // rows*304 pairs
    if (tid >= rows * 304) return;
    int r = tid / 304, p = tid % 304;
    uintT v = 0;
    if (p < 301) {
        float2 f = *(const float2*)&src[(size_t)r * 602 + 2 * p];
        v = (uintT)f2bf(f.x) | ((uintT)f2bf(f.y) << 16);
    }
    *(uintT*)&dst[(size_t)r * 1216 + 2 * p] = v;
}

// ---- fused x1 pass: read x1 once; write bf16 self-copy into X1cat cols [0,608)
// ---- for all 25 member rows AND the 25-row mean into X0cat cols [608,1216) ----
__global__ void prep_x1(const float* __restrict__ x1, ushortT* __restrict__ X1cat,
                        ushortT* __restrict__ X0cat) {
    int tid = blockIdx.x * 256 + threadIdx.x;       // 1024*304 pairs
    if (tid >= 1024 * 304) return;
    int r = tid / 304, p = tid % 304;
    uintT mv = 0;
    if (p < 301) {
        float s0 = 0.f, s1 = 0.f;
        const float* src = x1 + (size_t)r * 25 * 602 + 2 * p;
        ushortT* dst = X1cat + (size_t)r * 25 * 1216 + 2 * p;
#pragma unroll 5
        for (int j = 0; j < 25; ++j) {
            float2 f = *(const float2*)(src + (size_t)j * 602);
            s0 += f.x; s1 += f.y;
            *(uintT*)(dst + (size_t)j * 1216) =
                (uintT)f2bf(f.x) | ((uintT)f2bf(f.y) << 16);
        }
        mv = (uintT)f2bf(s0 * 0.04f) | ((uintT)f2bf(s1 * 0.04f) << 16);
    } else {
        ushortT* dst = X1cat + (size_t)r * 25 * 1216 + 2 * p;
#pragma unroll 5
        for (int j = 0; j < 25; ++j)
            *(uintT*)(dst + (size_t)j * 1216) = 0;   // pad cols 602..607
    }
    *(uintT*)&X0cat[(size_t)r * 1216 + 608 + 2 * p] = mv;
}

// ------ x2 neighbor mean (fan=10, unrolled) -> bf16 into X1cat cols [608,1216) ------
__global__ void agg_mean10(const float* __restrict__ src, ushortT* __restrict__ dst) {
    int tid = blockIdx.x * 256 + threadIdx.x;       // 25600*304 pairs
    if (tid >= 25600 * 304) return;
    int r = tid / 304, p = tid % 304;
    uintT v = 0;
    if (p < 301) {
        float s0 = 0.f, s1 = 0.f;
        const float* base = src + (size_t)r * 10 * 602 + 2 * p;
#pragma unroll
        for (int j = 0; j < 10; ++j) {
            float2 f = *(const float2*)(base + (size_t)j * 602);
            s0 += f.x; s1 += f.y;
        }
        v = (uintT)f2bf(s0 * 0.1f) | ((uintT)f2bf(s1 * 0.1f) << 16);
    }
    *(uintT*)&dst[(size_t)r * 1216 + 608 + 2 * p] = v;
}

__global__ void zero_hm(float* __restrict__ hm) {
    int tid = blockIdx.x * 256 + threadIdx.x;       // 65536 x f32x4 = 1 MB
    ((f32x4*)hm)[tid] = f32x4{0.f, 0.f, 0.f, 0.f};
}

// --------- 64x256-tile bf16 MFMA GEMM, K=1216, single N-pass, relu ---------
// blocks [0,blocks1): A1 rows -> relu -> atomicAdd into HM[row/25] (mean accum)
// blocks [blocks1,..): A0 rows -> relu -> H0 (f32)
__global__ __launch_bounds__(256) void gemm_relu(
    const ushortT* __restrict__ A1, const ushortT* __restrict__ A0,
    const ushortT* __restrict__ Bt,
    float* __restrict__ HM, float* __restrict__ H0, int blocks1) {
    __shared__ ushortT sA[64 * 32];
    __shared__ ushortT sB[256 * 32];
    const int K = 1216;
    int bid = blockIdx.x;
    bool neigh = bid < blocks1;
    const ushortT* A; int mt;
    if (neigh) { A = A1; mt = bid; }
    else { A = A0; mt = bid - blocks1; }
    int m0 = mt * 64;
    int t = threadIdx.x, w = t >> 6, l = t & 63;

    // staging: thread t loads 16B; row = t/4, col byte = (t%4)*16 (linear in t)
    const ushortT* Ag = A + (size_t)(m0 + (t >> 2)) * K + (t & 3) * 8;
    const ushortT* Bg = Bt + (size_t)(t >> 2) * K + (t & 3) * 8;
    ushortT* sAw = sA + w * 512;              // wave-uniform LDS bases
    ushortT* sBw = sB + w * 512;

    int lm = l & 15, quad = l >> 4;
    int aoff = lm * 32 + quad * 8;
    int boff = (w * 64 + lm) * 32 + quad * 8;

    f32x4 acc[4][4] = {};
    for (int k0 = 0; k0 < K; k0 += 32) {
        __syncthreads();
        gld16(Ag + k0, sAw);
#pragma unroll
        for (int i = 0; i < 4; ++i)           // B rows i*64 + t/4
            gld16(Bg + (size_t)i * 64 * K + k0, sBw + i * 2048);
        __syncthreads();
        bf16x8 af[4], bfr[4];
#pragma unroll
        for (int i = 0; i < 4; ++i) {
            af[i] = *(const bf16x8*)(sA + aoff + i * 512);
            bfr[i] = *(const bf16x8*)(sB + boff + i * 512);
        }
#pragma unroll
        for (int mi = 0; mi < 4; ++mi)
#pragma unroll
            for (int ni = 0; ni < 4; ++ni)
                acc[mi][ni] = __builtin_amdgcn_mfma_f32_16x16x32_bf16(
                    af[mi], bfr[ni], acc[mi][ni], 0, 0, 0);
    }

#pragma unroll
    for (int mi = 0; mi < 4; ++mi) {
        int rb = m0 + mi * 16 + quad * 4;
#pragma unroll
        for (int ni = 0; ni < 4; ++ni) {
            int c = w * 64 + ni * 16 + lm;
            f32x4 v = acc[mi][ni];
#pragma unroll
            for (int r = 0; r < 4; ++r) {
                float x = v[r] > 0.f ? v[r] : 0.f;   // relu
                if (neigh)
                    atomicAdd(&HM[(size_t)((uintT)(rb + r) / 25u) * 256 + c], x);
                else
                    H0[(size_t)(rb + r) * 256 + c] = x;
            }
        }
    }
}

// --------- head: (h0 ++ 0.04*HM) -> 41 logits -> log_softmax -> f32 out ---------
__global__ __launch_bounds__(64) void final_k(
    const float* __restrict__ H0, const float* __restrict__ HM,
    const float* __restrict__ W1, float* __restrict__ out) {
    __shared__ float xrow[512];
    int r = blockIdx.x;     // 0..1023
    int l = threadIdx.x;    // 0..63
    for (int c = l; c < 256; c += 64) {
        xrow[c] = H0[r * 256 + c];
        xrow[256 + c] = HM[r * 256 + c] * 0.04f;
    }
    __syncthreads();
    float v = -__builtin_inff();
    if (l < 41) {
        float s = 0.f;
        for (int k = 0; k < 512; ++k)
            s += xrow[k] * W1[k * 41 + l];
        v = s;
    }
    float m = v;
    for (int off = 32; off; off >>= 1) m = fmaxf(m, __shfl_xor(m, off, 64));
    float e = (l < 41) ? __expf(v - m) : 0.f;
    float sum = e;
    for (int off = 32; off; off >>= 1) sum += __shfl_xor(sum, off, 64);
    float lse = __logf(sum);
    if (l < 41) out[r * 41 + l] = (v - m) - lse;
}

extern "C" void kernel_launch(void* const* d_in, const int* in_sizes, int n_in,
                              void* d_out, int out_size, void* d_ws, size_t ws_size,
                              hipStream_t stream) {
    const float* x0 = (const float*)d_in[0];   // [1024][602]
    const float* x1 = (const float*)d_in[1];   // [25600][602]
    const float* x2 = (const float*)d_in[2];   // [256000][602]
    const float* W0 = (const float*)d_in[3];   // [1204][256]
    const float* W1 = (const float*)d_in[4];   // [512][41]
    float* out = (float*)d_out;                // [1024][41]
    char* ws = (char*)d_ws;

    ushortT* X1cat = (ushortT*)(ws);                // 25600*1216*2 = 62,259,200
    ushortT* X0cat = (ushortT*)(ws + 62259200);     //  1024*1216*2 =  2,490,368
    ushortT* W0T   = (ushortT*)(ws + 64749568);     //   256*1216*2 =    622,592
    float*   hm    = (float*)(ws + 65372160);       //  1024*256*4  =  1,048,576
    float*   h0    = (float*)(ws + 66420736);       //  1024*256*4  =  1,048,576
                                                    // total ~67.5 MB

    prep_w<<<(256 * 1216 + 255) / 256, 256, 0, stream>>>(W0, W0T);
    copy_pad<<<(1024 * 304 + 255) / 256, 256, 0, stream>>>(x0, X0cat, 1024);
    prep_x1<<<(1024 * 304 + 255) / 256, 256, 0, stream>>>(x1, X1cat, X0cat);
    agg_mean10<<<(25600 * 304 + 255) / 256, 256, 0, stream>>>(x2, X1cat);
    zero_hm<<<256, 256, 0, stream>>>(hm);
    gemm_relu<<<400 + 16, 256, 0, stream>>>(X1cat, X0cat, W0T, hm, h0, 400);
    final_k<<<1024, 64, 0, stream>>>(h0, hm, W1, out);
}